// Round 4
// baseline (218.362 us; speedup 1.0000x reference)
//
#include <hip/hip_runtime.h>
#include <math.h>

#define NPTS 16384
#define DIM  16
#define KH   32                 // fp16 direct: [a18, 0*14] (fp16 rounding ok: ~1e-3 final err vs 3.8e-2 threshold)
#define CSPLIT 16
#define COLS_PER_BLOCK (NPTS / CSPLIT)        // 1024
#define CHUNK_COLS 256
#define NCHUNK (COLS_PER_BLOCK / CHUNK_COLS)  // 4
#define JT_PER_CHUNK (CHUNK_COLS / 16)        // 16
#define ROWS_PER_BLOCK 512
#define RBLK (NPTS / ROWS_PER_BLOCK)          // 32
#define MT 8                                   // 16-row M-tiles per wave (128 rows/wave)
#define NBLOCKS (2 * RBLK * CSPLIT)            // 1024

typedef _Float16 f16x8 __attribute__((ext_vector_type(8)));
typedef float    f32x4 __attribute__((ext_vector_type(4)));

// ---------------------------------------------------------------------------
// prep: augmented vectors with <x',y'> = -0.5*rx*ry*||x-y||^2, cast to fp16.
//   x' = rx*[x, -||x||^2/2, 1]   y' = ry*[y, 1, -||y||^2/2]   (K padded to 32)
// FRAGMENT-PACKED: point p -> group g=p/16, c=p%16; half-offset
//   g*512 + quad*128 + c*8  holds k = quad*8+j  == g*512 + lane*8
// so pairs reads every fragment as one linear b128 (0 bank conflicts).
// Also inits the atomicMin array + the block-done counter (ws is re-poisoned
// to 0xAA before every launch, so this must happen every call).
// ---------------------------------------------------------------------------
__global__ __launch_bounds__(256) void prep_kernel(const float* __restrict__ s1,
                                                   const float* __restrict__ s2,
                                                   _Float16* __restrict__ Xp,
                                                   _Float16* __restrict__ Yp,
                                                   unsigned int* __restrict__ rowfinal,
                                                   unsigned int* __restrict__ counter) {
    int b = blockIdx.x, tid = threadIdx.x;
    int idx = b * 256 + tid;                // 0..32767
    rowfinal[idx] = 0xFFFFFFFFu;            // uint-min identity
    if (idx == 0) *counter = 0u;

    int isX = (b < 64);
    const float* src = isX ? s1 : s2;
    _Float16* dst = isX ? Xp : Yp;
    int p = (isX ? b : b - 64) * 256 + tid;

    const float4* s4 = (const float4*)(src + (size_t)p * DIM);
    float4 A = s4[0], B = s4[1], C = s4[2], D = s4[3];
    float v[DIM] = {A.x,A.y,A.z,A.w, B.x,B.y,B.z,B.w,
                    C.x,C.y,C.z,C.w, D.x,D.y,D.z,D.w};
    float n2 = 0.f;
#pragma unroll
    for (int k = 0; k < DIM; ++k) n2 = fmaf(v[k], v[k], n2);
    float r = 1.0f / (1.0f - n2);           // norms < 0.7 -> safe
    float a[18];
#pragma unroll
    for (int k = 0; k < DIM; ++k) a[k] = r * v[k];
    if (isX) { a[16] = -0.5f * r * n2; a[17] = r; }
    else     { a[16] = r;              a[17] = -0.5f * r * n2; }

    __attribute__((aligned(16))) _Float16 buf[KH];
#pragma unroll
    for (int k = 0; k < 18; ++k) buf[k] = (_Float16)a[k];
#pragma unroll
    for (int k = 18; k < KH; ++k) buf[k] = (_Float16)0.f;

    int g = p >> 4, c = p & 15;
    const uint4* b4 = (const uint4*)buf;
#pragma unroll
    for (int q = 0; q < 4; ++q) {
        size_t off = (size_t)g * 512 + (size_t)q * 128 + (size_t)c * 8;
        *(uint4*)(dst + off) = b4[q];
    }
}

// ---------------------------------------------------------------------------
// pairs (+fused finalize): 1024 blocks (2 passes x 32 row-blocks x 16
// col-splits) = 4 blocks/CU. Wave holds 128 rows of A in registers (8 b128
// global loads), sweeps 1024 cols in 16KB LDS chunks (global_load_lds w=16).
// Per 16-col tile: 1 ds_read_b128 + 8 independent MFMA + 32 fmax (running
// per-lane row max; arcosh monotone => max raw accumulators, no sqrt/log).
// Cross-lane reduce once per block -> atomicMin uint (acc<=0: float-max ==
// uint-min). Last-finished block (device-scope counter) computes arcosh+mean.
// ---------------------------------------------------------------------------
__global__ __launch_bounds__(256, 4) void pairs_kernel(const _Float16* __restrict__ Xp,
                                                       const _Float16* __restrict__ Yp,
                                                       unsigned int* __restrict__ rowfinal,
                                                       unsigned int* __restrict__ counter,
                                                       float* __restrict__ out) {
    __shared__ __align__(16) _Float16 Bs[CHUNK_COLS * KH];   // 16 KB

    const int b = blockIdx.x;
    const int pass = b >> 9;                 // 512 blocks per pass
    const int within = b & 511;
    const int r  = within >> 4;              // row-block 0..31
    const int cs = within & 15;              // col-split 0..15

    const _Float16* Aset = pass ? Yp : Xp;
    const _Float16* Bset = pass ? Xp : Yp;
    unsigned int* outMin = rowfinal + pass * NPTS;

    const int tid = threadIdx.x;
    const int lane = tid & 63, w = tid >> 6;
    const int c = lane & 15, quad = lane >> 4;

    // ---- A fragments: 128 rows/wave resident in registers for the whole sweep
    f16x8 af[MT];
#pragma unroll
    for (int t = 0; t < MT; ++t) {
        int g = r * 32 + w * 8 + t;
        af[t] = *(const f16x8*)&Aset[(size_t)g * 512 + (size_t)lane * 8];
    }

    f32x4 rowmax[MT];
#pragma unroll
    for (int t = 0; t < MT; ++t)
        rowmax[t] = (f32x4){-INFINITY, -INFINITY, -INFINITY, -INFINITY};

    const char* Bbase = (const char*)Bset + (size_t)cs * ((size_t)COLS_PER_BLOCK * KH * 2);

    for (int ch = 0; ch < NCHUNK; ++ch) {
        const char* gsrc = Bbase + (size_t)ch * (CHUNK_COLS * KH * 2) + (size_t)tid * 16;
        char* lb = (char*)Bs + (size_t)tid * 16;
#pragma unroll
        for (int e = 0; e < 4; ++e) {
            __builtin_amdgcn_global_load_lds(
                (const __attribute__((address_space(1))) unsigned int*)(gsrc + e * 4096),
                (__attribute__((address_space(3))) unsigned int*)(lb + e * 4096),
                16, 0, 0);
        }
        __syncthreads();

#pragma unroll 4
        for (int jt = 0; jt < JT_PER_CHUNK; ++jt) {
            f16x8 bf = *(const f16x8*)&Bs[jt * 512 + lane * 8];
#pragma unroll
            for (int t = 0; t < MT; ++t) {
                f32x4 acc = (f32x4){0.f, 0.f, 0.f, 0.f};
                acc = __builtin_amdgcn_mfma_f32_16x16x32_f16(af[t], bf, acc, 0, 0, 0);
                rowmax[t][0] = fmaxf(rowmax[t][0], acc[0]);
                rowmax[t][1] = fmaxf(rowmax[t][1], acc[1]);
                rowmax[t][2] = fmaxf(rowmax[t][2], acc[2]);
                rowmax[t][3] = fmaxf(rowmax[t][3], acc[3]);
            }
        }
        __syncthreads();
    }

    // ---- once-per-block: reduce over 16 c-lanes, atomicMin into rowfinal
    // C/D layout (measured): col = lane&15, row = quad*4 + reg.
#pragma unroll
    for (int t = 0; t < MT; ++t) {
#pragma unroll
        for (int e = 0; e < 4; ++e) {
            float m = rowmax[t][e];
            m = fmaxf(m, __shfl_xor(m, 1, 64));
            m = fmaxf(m, __shfl_xor(m, 2, 64));
            m = fmaxf(m, __shfl_xor(m, 4, 64));
            m = fmaxf(m, __shfl_xor(m, 8, 64));
            if (c == 0) {
                int row = ((r * 32 + w * 8 + t) << 4) + quad * 4 + e;
                atomicMin(&outMin[row], __float_as_uint(m));
            }
        }
    }

    // ---- last-block-done finalize: arcosh + mean of the 32768 winners
    __threadfence();
    __shared__ int isLast;
    if (tid == 0) {
        unsigned int old = __hip_atomic_fetch_add(counter, 1u, __ATOMIC_ACQ_REL,
                                                  __HIP_MEMORY_SCOPE_AGENT);
        isLast = (old == NBLOCKS - 1);
    }
    __syncthreads();
    if (isLast) {
        float sum = 0.f;
        for (int k = 0; k < (2 * NPTS) / 256; ++k) {
            int i = tid + k * 256;
            unsigned int ub = __hip_atomic_load(&rowfinal[i], __ATOMIC_RELAXED,
                                                __HIP_MEMORY_SCOPE_AGENT);
            float f = __uint_as_float(ub);          // max accumulator (<= 0 up to fp16 noise)
            float t = fmaxf(-4.0f * f, 0.0f);       // u-1, clamped (NaN guard)
            sum += log1pf(t + sqrtf(t * (t + 2.0f)));   // arcosh(1+t)
        }
        __shared__ float sred[256];
        sred[tid] = sum;
        __syncthreads();
        for (int s = 128; s > 0; s >>= 1) {
            if (tid < s) sred[tid] += sred[tid + s];
            __syncthreads();
        }
        if (tid == 0) out[0] = sred[0] * (1.0f / NPTS);
    }
}

// ---------------------------------------------------------------------------
extern "C" void kernel_launch(void* const* d_in, const int* in_sizes, int n_in,
                              void* d_out, int out_size, void* d_ws, size_t ws_size,
                              hipStream_t stream) {
    const float* set1 = (const float*)d_in[0];
    const float* set2 = (const float*)d_in[1];
    float* out = (float*)d_out;

    // ws: Xp 1MB + Yp 1MB (fp16 fragment-packed) + rowfinal 128KB + counter
    _Float16* Xp = (_Float16*)d_ws;
    _Float16* Yp = Xp + (size_t)NPTS * KH;
    unsigned int* rowfinal = (unsigned int*)(Yp + (size_t)NPTS * KH);
    unsigned int* counter = rowfinal + 2 * NPTS;

    prep_kernel<<<128, 256, 0, stream>>>(set1, set2, Xp, Yp, rowfinal, counter);
    pairs_kernel<<<NBLOCKS, 256, 0, stream>>>(Xp, Yp, rowfinal, counter, out);
}

// Round 5
// 94.979 us; speedup vs baseline: 2.2991x; 2.2991x over previous
//
#include <hip/hip_runtime.h>
#include <math.h>

#define NPTS 16384
#define DIM  16
#define KH   32                 // fp16 direct: [a18, 0*14]; fp16 rounding ~1e-3 final err vs 3.8e-2 threshold
#define CSPLIT 16
#define COLS_PER_BLOCK (NPTS / CSPLIT)        // 1024
#define CHUNK_COLS 256
#define NCHUNK (COLS_PER_BLOCK / CHUNK_COLS)  // 4
#define JT_PER_CHUNK (CHUNK_COLS / 16)        // 16
#define ROWS_PER_BLOCK 512
#define RBLK (NPTS / ROWS_PER_BLOCK)          // 32
#define MT 8                                   // 16-row M-tiles per wave (128 rows/wave)
#define NBLOCKS (2 * RBLK * CSPLIT)            // 1024

typedef _Float16 f16x8 __attribute__((ext_vector_type(8)));
typedef float    f32x4 __attribute__((ext_vector_type(4)));

// ---------------------------------------------------------------------------
// prep: augmented vectors with <x',y'> = -0.5*rx*ry*||x-y||^2, cast to fp16.
//   x' = rx*[x, -||x||^2/2, 1]   y' = ry*[y, 1, -||y||^2/2]   (K padded to 32)
// FRAGMENT-PACKED: point p -> group g=p/16, c=p%16; half-offset
//   g*512 + quad*128 + c*8  (== g*512 + lane*8) holds k = quad*8+j, so pairs
// reads every fragment as one linear ds_read_b128 / global b128: 0 conflicts.
// Also inits the atomicMin array and zeroes the output scalar (d_ws/d_out are
// re-poisoned to 0xAA before every launch).
// ---------------------------------------------------------------------------
__global__ __launch_bounds__(256) void prep_kernel(const float* __restrict__ s1,
                                                   const float* __restrict__ s2,
                                                   _Float16* __restrict__ Xp,
                                                   _Float16* __restrict__ Yp,
                                                   unsigned int* __restrict__ rowfinal,
                                                   float* __restrict__ out) {
    int b = blockIdx.x, tid = threadIdx.x;
    int idx = b * 256 + tid;                // 0..32767
    rowfinal[idx] = 0xFFFFFFFFu;            // uint-min identity
    if (idx == 0) out[0] = 0.f;

    int isX = (b < 64);
    const float* src = isX ? s1 : s2;
    _Float16* dst = isX ? Xp : Yp;
    int p = (isX ? b : b - 64) * 256 + tid;

    const float4* s4 = (const float4*)(src + (size_t)p * DIM);
    float4 A = s4[0], B = s4[1], C = s4[2], D = s4[3];
    float v[DIM] = {A.x,A.y,A.z,A.w, B.x,B.y,B.z,B.w,
                    C.x,C.y,C.z,C.w, D.x,D.y,D.z,D.w};
    float n2 = 0.f;
#pragma unroll
    for (int k = 0; k < DIM; ++k) n2 = fmaf(v[k], v[k], n2);
    float r = 1.0f / (1.0f - n2);           // norms < 0.7 -> safe
    float a[18];
#pragma unroll
    for (int k = 0; k < DIM; ++k) a[k] = r * v[k];
    if (isX) { a[16] = -0.5f * r * n2; a[17] = r; }
    else     { a[16] = r;              a[17] = -0.5f * r * n2; }

    __attribute__((aligned(16))) _Float16 buf[KH];
#pragma unroll
    for (int k = 0; k < 18; ++k) buf[k] = (_Float16)a[k];
#pragma unroll
    for (int k = 18; k < KH; ++k) buf[k] = (_Float16)0.f;

    int g = p >> 4, c = p & 15;
    const uint4* b4 = (const uint4*)buf;
#pragma unroll
    for (int q = 0; q < 4; ++q) {
        size_t off = (size_t)g * 512 + (size_t)q * 128 + (size_t)c * 8;
        *(uint4*)(dst + off) = b4[q];
    }
}

// ---------------------------------------------------------------------------
// pairs: 1024 blocks (2 passes x 32 row-blocks x 16 col-splits) = 4/CU.
// Round-3 proven skeleton: lb(256,2) — do NOT cap registers (lb(256,4) in r4
// forced VGPR 88->60, demoted af[]/rowmax[] to memory, 2.8x regression).
// Wave holds 128 rows of A in registers (8 b128 global loads), sweeps 1024
// cols in 16KB LDS chunks (global_load_lds w=16). Per 16-col tile:
// 1 ds_read_b128 + 8 independent MFMA (C = hoisted zero reg) + 32 fmax.
// arcosh monotone => running max of raw accumulators; cross-lane reduce once
// per block -> atomicMin uint (acc<=0: float-max == uint-min).
// ---------------------------------------------------------------------------
__global__ __launch_bounds__(256, 2) void pairs_kernel(const _Float16* __restrict__ Xp,
                                                       const _Float16* __restrict__ Yp,
                                                       unsigned int* __restrict__ rowfinal) {
    __shared__ __align__(16) _Float16 Bs[CHUNK_COLS * KH];   // 16 KB

    const int b = blockIdx.x;
    const int pass = b >> 9;                 // 512 blocks per pass
    const int within = b & 511;
    const int r  = within >> 4;              // row-block 0..31
    const int cs = within & 15;              // col-split 0..15

    const _Float16* Aset = pass ? Yp : Xp;
    const _Float16* Bset = pass ? Xp : Yp;
    unsigned int* outMin = rowfinal + pass * NPTS;

    const int tid = threadIdx.x;
    const int lane = tid & 63, w = tid >> 6;
    const int c = lane & 15, quad = lane >> 4;

    // ---- A fragments: 128 rows/wave resident in registers for the whole sweep
    f16x8 af[MT];
#pragma unroll
    for (int t = 0; t < MT; ++t) {
        int g = r * 32 + w * 8 + t;
        af[t] = *(const f16x8*)&Aset[(size_t)g * 512 + (size_t)lane * 8];
    }

    f32x4 rowmax[MT];
#pragma unroll
    for (int t = 0; t < MT; ++t)
        rowmax[t] = (f32x4){-INFINITY, -INFINITY, -INFINITY, -INFINITY};

    const f32x4 zero = (f32x4){0.f, 0.f, 0.f, 0.f};
    const char* Bbase = (const char*)Bset + (size_t)cs * ((size_t)COLS_PER_BLOCK * KH * 2);

    for (int ch = 0; ch < NCHUNK; ++ch) {
        const char* gsrc = Bbase + (size_t)ch * (CHUNK_COLS * KH * 2) + (size_t)tid * 16;
        char* lb = (char*)Bs + (size_t)tid * 16;
#pragma unroll
        for (int e = 0; e < 4; ++e) {
            __builtin_amdgcn_global_load_lds(
                (const __attribute__((address_space(1))) unsigned int*)(gsrc + e * 4096),
                (__attribute__((address_space(3))) unsigned int*)(lb + e * 4096),
                16, 0, 0);
        }
        __syncthreads();

#pragma unroll 4
        for (int jt = 0; jt < JT_PER_CHUNK; ++jt) {
            f16x8 bf = *(const f16x8*)&Bs[jt * 512 + lane * 8];
#pragma unroll
            for (int t = 0; t < MT; ++t) {
                f32x4 acc = __builtin_amdgcn_mfma_f32_16x16x32_f16(af[t], bf, zero, 0, 0, 0);
                rowmax[t][0] = fmaxf(rowmax[t][0], acc[0]);
                rowmax[t][1] = fmaxf(rowmax[t][1], acc[1]);
                rowmax[t][2] = fmaxf(rowmax[t][2], acc[2]);
                rowmax[t][3] = fmaxf(rowmax[t][3], acc[3]);
            }
        }
        __syncthreads();
    }

    // ---- once-per-block: reduce over 16 c-lanes, atomicMin into rowfinal
    // C/D layout (measured): col = lane&15, row = quad*4 + reg.
#pragma unroll
    for (int t = 0; t < MT; ++t) {
#pragma unroll
        for (int e = 0; e < 4; ++e) {
            float m = rowmax[t][e];
            m = fmaxf(m, __shfl_xor(m, 1, 64));
            m = fmaxf(m, __shfl_xor(m, 2, 64));
            m = fmaxf(m, __shfl_xor(m, 4, 64));
            m = fmaxf(m, __shfl_xor(m, 8, 64));
            if (c == 0) {
                int row = ((r * 32 + w * 8 + t) << 4) + quad * 4 + e;
                atomicMin(&outMin[row], __float_as_uint(m));
            }
        }
    }
}

// ---------------------------------------------------------------------------
// finalize: 32768 winners -> arcosh -> mean -> atomicAdd scalar.
// t = -4*maxacc = u-1 >= 0 (clamped: fp16 noise can push acc slightly > 0);
// arcosh(1+t) = log1p(t + sqrt(t*(t+2)))
// ---------------------------------------------------------------------------
__global__ __launch_bounds__(256) void finalize_kernel(const unsigned int* __restrict__ rowfinal,
                                                       float* __restrict__ out) {
    int idx = blockIdx.x * 256 + threadIdx.x;
    float f = __uint_as_float(rowfinal[idx]);     // max accumulator
    float t = fmaxf(-4.0f * f, 0.0f);
    float d = log1pf(t + sqrtf(t * (t + 2.0f)));
    float val = d * (1.0f / NPTS);

    __shared__ float sred[256];
    sred[threadIdx.x] = val;
    __syncthreads();
    for (int s = 128; s > 0; s >>= 1) {
        if (threadIdx.x < s) sred[threadIdx.x] += sred[threadIdx.x + s];
        __syncthreads();
    }
    if (threadIdx.x == 0) atomicAdd(out, sred[0]);
}

// ---------------------------------------------------------------------------
extern "C" void kernel_launch(void* const* d_in, const int* in_sizes, int n_in,
                              void* d_out, int out_size, void* d_ws, size_t ws_size,
                              hipStream_t stream) {
    const float* set1 = (const float*)d_in[0];
    const float* set2 = (const float*)d_in[1];
    float* out = (float*)d_out;

    // ws: Xp 1MB + Yp 1MB (fp16 fragment-packed) + rowfinal 128KB
    _Float16* Xp = (_Float16*)d_ws;
    _Float16* Yp = Xp + (size_t)NPTS * KH;
    unsigned int* rowfinal = (unsigned int*)(Yp + (size_t)NPTS * KH);

    prep_kernel<<<128, 256, 0, stream>>>(set1, set2, Xp, Yp, rowfinal, out);
    pairs_kernel<<<NBLOCKS, 256, 0, stream>>>(Xp, Yp, rowfinal);
    finalize_kernel<<<2 * NPTS / 256, 256, 0, stream>>>(rowfinal, out);
}

// Round 6
// 92.823 us; speedup vs baseline: 2.3525x; 1.0232x over previous
//
#include <hip/hip_runtime.h>
#include <math.h>

#define NPTS 16384
#define DIM  16
#define KH   32                 // fp16 direct: [a18, 0*14]; fp16 rounding ~1e-3 final err vs 3.8e-2 threshold
#define CSPLIT 16
#define COLS_PER_BLOCK (NPTS / CSPLIT)        // 1024
#define JT_TOTAL (COLS_PER_BLOCK / 16)        // 64
#define ROWS_PER_BLOCK 512
#define RBLK (NPTS / ROWS_PER_BLOCK)          // 32
#define MT 8                                   // 16-row M-tiles per wave (128 rows/wave)
#define NBLOCKS (2 * RBLK * CSPLIT)            // 1024

typedef _Float16 f16x8 __attribute__((ext_vector_type(8)));
typedef float    f32x4 __attribute__((ext_vector_type(4)));

// ---------------------------------------------------------------------------
// prep: augmented vectors with <x',y'> = -0.5*rx*ry*||x-y||^2, cast to fp16.
//   x' = rx*[x, -||x||^2/2, 1]   y' = ry*[y, 1, -||y||^2/2]   (K padded to 32)
// FRAGMENT-PACKED: point p -> group g=p/16, c=p%16; half-offset
//   g*512 + quad*128 + c*8  (== g*512 + lane*8) holds k = quad*8+j, so pairs
// reads every fragment as one linear ds_read_b128 / global b128: 0 conflicts.
// Also inits the atomicMin array and zeroes the output scalar (d_ws/d_out are
// re-poisoned to 0xAA before every launch).
// ---------------------------------------------------------------------------
__global__ __launch_bounds__(256) void prep_kernel(const float* __restrict__ s1,
                                                   const float* __restrict__ s2,
                                                   _Float16* __restrict__ Xp,
                                                   _Float16* __restrict__ Yp,
                                                   unsigned int* __restrict__ rowfinal,
                                                   float* __restrict__ out) {
    int b = blockIdx.x, tid = threadIdx.x;
    int idx = b * 256 + tid;                // 0..32767
    rowfinal[idx] = 0xFFFFFFFFu;            // uint-min identity
    if (idx == 0) out[0] = 0.f;

    int isX = (b < 64);
    const float* src = isX ? s1 : s2;
    _Float16* dst = isX ? Xp : Yp;
    int p = (isX ? b : b - 64) * 256 + tid;

    const float4* s4 = (const float4*)(src + (size_t)p * DIM);
    float4 A = s4[0], B = s4[1], C = s4[2], D = s4[3];
    float v[DIM] = {A.x,A.y,A.z,A.w, B.x,B.y,B.z,B.w,
                    C.x,C.y,C.z,C.w, D.x,D.y,D.z,D.w};
    float n2 = 0.f;
#pragma unroll
    for (int k = 0; k < DIM; ++k) n2 = fmaf(v[k], v[k], n2);
    float r = 1.0f / (1.0f - n2);           // norms < 0.7 -> safe
    float a[18];
#pragma unroll
    for (int k = 0; k < DIM; ++k) a[k] = r * v[k];
    if (isX) { a[16] = -0.5f * r * n2; a[17] = r; }
    else     { a[16] = r;              a[17] = -0.5f * r * n2; }

    __attribute__((aligned(16))) _Float16 buf[KH];
#pragma unroll
    for (int k = 0; k < 18; ++k) buf[k] = (_Float16)a[k];
#pragma unroll
    for (int k = 18; k < KH; ++k) buf[k] = (_Float16)0.f;

    int g = p >> 4, c = p & 15;
    const uint4* b4 = (const uint4*)buf;
#pragma unroll
    for (int q = 0; q < 4; ++q) {
        size_t off = (size_t)g * 512 + (size_t)q * 128 + (size_t)c * 8;
        *(uint4*)(dst + off) = b4[q];
    }
}

// ---------------------------------------------------------------------------
// pairs: 1024 blocks (2 passes x 32 row-blocks x 16 col-splits), 2 blocks/CU
// (64 KB LDS each). Wave holds 128 rows of A in registers (8 b128 global
// loads). The ENTIRE 1024-col B-stripe (64 KB) is staged to LDS once via
// global_load_lds w=16, ONE __syncthreads, then 64 jt iterations of pure
// ds_read_b128 + 8 independent MFMA + 32 fmax with no further barriers
// (r5 had 8 barriers/block chunking 16KB — barrier drain was the gap to the
// 16.6us MFMA floor). lb(256,2): do NOT cap VGPRs (r4: lb(256,4) demoted
// af[]/rowmax[] to memory, 2.8x regression). arcosh monotone => running max
// of raw accumulators; cross-lane reduce once per block -> atomicMin uint
// (acc<=0: float-max == uint-min).
// ---------------------------------------------------------------------------
__global__ __launch_bounds__(256, 2) void pairs_kernel(const _Float16* __restrict__ Xp,
                                                       const _Float16* __restrict__ Yp,
                                                       unsigned int* __restrict__ rowfinal) {
    __shared__ __align__(16) _Float16 Bs[COLS_PER_BLOCK * KH];   // 64 KB

    const int b = blockIdx.x;
    const int pass = b >> 9;                 // 512 blocks per pass
    const int within = b & 511;
    const int r  = within >> 4;              // row-block 0..31
    const int cs = within & 15;              // col-split 0..15

    const _Float16* Aset = pass ? Yp : Xp;
    const _Float16* Bset = pass ? Xp : Yp;
    unsigned int* outMin = rowfinal + pass * NPTS;

    const int tid = threadIdx.x;
    const int lane = tid & 63, w = tid >> 6;
    const int c = lane & 15, quad = lane >> 4;

    // ---- stage the whole 64 KB B-stripe: 16 direct-to-LDS DMAs per thread
    {
        const char* gsrc = (const char*)Bset + (size_t)cs * (COLS_PER_BLOCK * KH * 2)
                         + (size_t)tid * 16;
        char* lb = (char*)Bs + (size_t)tid * 16;
#pragma unroll
        for (int e = 0; e < 16; ++e) {
            __builtin_amdgcn_global_load_lds(
                (const __attribute__((address_space(1))) unsigned int*)(gsrc + e * 4096),
                (__attribute__((address_space(3))) unsigned int*)(lb + e * 4096),
                16, 0, 0);
        }
    }

    // ---- A fragments: 128 rows/wave resident in registers for the whole sweep
    f16x8 af[MT];
#pragma unroll
    for (int t = 0; t < MT; ++t) {
        int g = r * 32 + w * 8 + t;
        af[t] = *(const f16x8*)&Aset[(size_t)g * 512 + (size_t)lane * 8];
    }

    f32x4 rowmax[MT];
#pragma unroll
    for (int t = 0; t < MT; ++t)
        rowmax[t] = (f32x4){-INFINITY, -INFINITY, -INFINITY, -INFINITY};

    const f32x4 zero = (f32x4){0.f, 0.f, 0.f, 0.f};

    __syncthreads();   // single barrier: LDS stripe complete

#pragma unroll 4
    for (int jt = 0; jt < JT_TOTAL; ++jt) {
        f16x8 bf = *(const f16x8*)&Bs[jt * 512 + lane * 8];
#pragma unroll
        for (int t = 0; t < MT; ++t) {
            f32x4 acc = __builtin_amdgcn_mfma_f32_16x16x32_f16(af[t], bf, zero, 0, 0, 0);
            rowmax[t][0] = fmaxf(rowmax[t][0], acc[0]);
            rowmax[t][1] = fmaxf(rowmax[t][1], acc[1]);
            rowmax[t][2] = fmaxf(rowmax[t][2], acc[2]);
            rowmax[t][3] = fmaxf(rowmax[t][3], acc[3]);
        }
    }

    // ---- once-per-block: reduce over 16 c-lanes, atomicMin into rowfinal
    // C/D layout (measured): col = lane&15, row = quad*4 + reg.
#pragma unroll
    for (int t = 0; t < MT; ++t) {
#pragma unroll
        for (int e = 0; e < 4; ++e) {
            float m = rowmax[t][e];
            m = fmaxf(m, __shfl_xor(m, 1, 64));
            m = fmaxf(m, __shfl_xor(m, 2, 64));
            m = fmaxf(m, __shfl_xor(m, 4, 64));
            m = fmaxf(m, __shfl_xor(m, 8, 64));
            if (c == 0) {
                int row = ((r * 32 + w * 8 + t) << 4) + quad * 4 + e;
                atomicMin(&outMin[row], __float_as_uint(m));
            }
        }
    }
}

// ---------------------------------------------------------------------------
// finalize: 32768 winners -> arcosh -> mean -> atomicAdd scalar.
// t = -4*maxacc = u-1 >= 0 (clamped: fp16 noise can push acc slightly > 0);
// arcosh(1+t) = log1p(t + sqrt(t*(t+2)))
// ---------------------------------------------------------------------------
__global__ __launch_bounds__(256) void finalize_kernel(const unsigned int* __restrict__ rowfinal,
                                                       float* __restrict__ out) {
    int idx = blockIdx.x * 256 + threadIdx.x;
    float f = __uint_as_float(rowfinal[idx]);     // max accumulator
    float t = fmaxf(-4.0f * f, 0.0f);
    float d = log1pf(t + sqrtf(t * (t + 2.0f)));
    float val = d * (1.0f / NPTS);

    __shared__ float sred[256];
    sred[threadIdx.x] = val;
    __syncthreads();
    for (int s = 128; s > 0; s >>= 1) {
        if (threadIdx.x < s) sred[threadIdx.x] += sred[threadIdx.x + s];
        __syncthreads();
    }
    if (threadIdx.x == 0) atomicAdd(out, sred[0]);
}

// ---------------------------------------------------------------------------
extern "C" void kernel_launch(void* const* d_in, const int* in_sizes, int n_in,
                              void* d_out, int out_size, void* d_ws, size_t ws_size,
                              hipStream_t stream) {
    const float* set1 = (const float*)d_in[0];
    const float* set2 = (const float*)d_in[1];
    float* out = (float*)d_out;

    // ws: Xp 1MB + Yp 1MB (fp16 fragment-packed) + rowfinal 128KB
    _Float16* Xp = (_Float16*)d_ws;
    _Float16* Yp = Xp + (size_t)NPTS * KH;
    unsigned int* rowfinal = (unsigned int*)(Yp + (size_t)NPTS * KH);

    prep_kernel<<<128, 256, 0, stream>>>(set1, set2, Xp, Yp, rowfinal, out);
    pairs_kernel<<<NBLOCKS, 256, 0, stream>>>(Xp, Yp, rowfinal);
    finalize_kernel<<<2 * NPTS / 256, 256, 0, stream>>>(rowfinal, out);
}